// Round 1
// baseline (231.966 us; speedup 1.0000x reference)
//
#include <hip/hip_runtime.h>

#define POOL 7
#define NCH 256
#define NBOX 1000
#define PER_BOX (NCH * POOL * POOL)  // 12544
#define TOTAL (NBOX * PER_BOX)        // 12,544,000
#define TOTAL4 (TOTAL / 4)            // 3,136,000

// Level thresholds on a = h*w for roi_level = round(4 + log2(sqrt(a)*1024/224)),
// clipped to [2,5]. level >= k+1  <=>  a >= (224/1024)^2 * 2^(2k-7).
// (224/1024)^2 = 0.0478515625 exactly.
#define T2 0.0059814453125f   // -> level >= 3
#define T3 0.02392578125f     // -> level >= 4
#define T4 0.095703125f       // -> level >= 5

__global__ __launch_bounds__(256) void pyramid_roialign_kernel(
    const float* __restrict__ boxes,
    const float* __restrict__ f2,
    const float* __restrict__ f3,
    const float* __restrict__ f4,
    const float* __restrict__ f5,
    float* __restrict__ out)
{
    unsigned gid = blockIdx.x * blockDim.x + threadIdx.x;
    if (gid >= TOTAL4) return;
    unsigned base = gid * 4u;
    unsigned n = base / PER_BOX;          // box index (wave-uniform in practice)
    unsigned rem = base - n * PER_BOX;    // 0..12543, multiple of 4

    // Load box (broadcast within wave — same n for 3136 consecutive threads)
    const float* bx = boxes + n * 5u;
    float b0 = bx[0];
    float r0 = bx[1], r1 = bx[2], r2 = bx[3], r3 = bx[4];

    // roi_level from h = boxes[:,3]-boxes[:,1], w = boxes[:,4]-boxes[:,2]
    float a = (r2 - r0) * (r3 - r1);
    int lvl = (a >= T2) + (a >= T3) + (a >= T4);   // 0..3 == roi_level-2

    const float* fmap = (lvl == 0) ? f2 : (lvl == 1) ? f3 : (lvl == 2) ? f4 : f5;
    int H = 256 >> lvl;                    // H == W
    const float scales[4] = {0.25f, 0.125f, 0.0625f, 0.03125f};
    float scale = scales[lvl];

    int bidx = (int)b0;

    // _roi_align: rois = boxes[:,1:], x1=rois[:,0], y1=rois[:,1], x2=rois[:,2], y2=rois[:,3]
    float x1 = r0 * scale, y1 = r1 * scale;
    float x2 = r2 * scale, y2 = r3 * scale;
    float bw = fmaxf(x2 - x1, 1.0f) * (1.0f / POOL);
    float bh = fmaxf(y2 - y1, 1.0f) * (1.0f / POOL);

    float Hf = (float)H;
    float Hm1 = (float)(H - 1);
    unsigned planeStride = (unsigned)(H * H);
    unsigned batchOff = (unsigned)bidx * NCH * planeStride;

    float4 res;
    float* resp = &res.x;

    #pragma unroll
    for (int i = 0; i < 4; ++i) {
        unsigned e = rem + i;
        unsigned c = e / 49u;
        unsigned s = e - c * 49u;
        unsigned py = s / 7u;
        unsigned px = s - py * 7u;

        float y = y1 + ((float)py + 0.5f) * bh;
        float x = x1 + ((float)px + 0.5f) * bw;
        bool valid = (y > -1.0f) & (y < Hf) & (x > -1.0f) & (x < Hf);

        float yc = fminf(fmaxf(y, 0.0f), Hm1);
        float xc = fminf(fmaxf(x, 0.0f), Hm1);
        float y0f = floorf(yc);
        float x0f = floorf(xc);
        int y0 = (int)y0f;
        int x0 = (int)x0f;
        int y1i = min(y0 + 1, H - 1);
        int x1i = min(x0 + 1, H - 1);
        float ly = yc - y0f;
        float lx = xc - x0f;
        float hy = 1.0f - ly;
        float hx = 1.0f - lx;

        const float* plane = fmap + batchOff + c * planeStride;
        float v00 = plane[y0  * H + x0 ];
        float v01 = plane[y0  * H + x1i];
        float v10 = plane[y1i * H + x0 ];
        float v11 = plane[y1i * H + x1i];

        float r = (hy * hx) * v00 + (hy * lx) * v01 + (ly * hx) * v10 + (ly * lx) * v11;
        resp[i] = valid ? r : 0.0f;
    }

    *reinterpret_cast<float4*>(out + base) = res;
}

extern "C" void kernel_launch(void* const* d_in, const int* in_sizes, int n_in,
                              void* d_out, int out_size, void* d_ws, size_t ws_size,
                              hipStream_t stream) {
    const float* boxes = (const float*)d_in[0];
    const float* f2 = (const float*)d_in[1];
    const float* f3 = (const float*)d_in[2];
    const float* f4 = (const float*)d_in[3];
    const float* f5 = (const float*)d_in[4];
    float* out = (float*)d_out;

    int threads = 256;
    int blocks = (TOTAL4 + threads - 1) / threads;   // 12250
    pyramid_roialign_kernel<<<blocks, threads, 0, stream>>>(boxes, f2, f3, f4, f5, out);
}

// Round 2
// 201.844 us; speedup vs baseline: 1.1492x; 1.1492x over previous
//
#include <hip/hip_runtime.h>

#define POOL 7
#define NCH 256
#define NBOX 1000
#define PER_BOX (NCH * POOL * POOL)  // 12544 floats per box

// Level thresholds on a = h*w for roi_level = round(4 + log2(sqrt(a)*1024/224)),
// clipped to [2,5]. level >= k+1  <=>  a >= (224/1024)^2 * 2^(2k-7).
#define TL2 0.0059814453125f   // -> level >= 3
#define TL3 0.02392578125f     // -> level >= 4
#define TL4 0.095703125f       // -> level >= 5

// One block per box. Thread t owns channel t. All 49 samples per box lie in
// the 3x3 top-left corner of the plane (normalized coords, scale<=1/4 =>
// bin=1/7, max sample coord ~1.06 => y0,x0 in {0,1}, y1i,x1i <= 2).
// Bilinear weights are separable: wy depends only on py, wx only on px.
__global__ __launch_bounds__(256) void pyramid_roialign_kernel(
    const float* __restrict__ boxes,
    const float* __restrict__ f2,
    const float* __restrict__ f3,
    const float* __restrict__ f4,
    const float* __restrict__ f5,
    float* __restrict__ out)
{
    __shared__ __align__(16) float outLds[PER_BOX];   // 49 KB -> 3 blocks/CU

    const int n = blockIdx.x;
    const int t = threadIdx.x;

    // Box params (wave-uniform broadcast loads)
    const float* bx = boxes + n * 5;
    const float b0 = bx[0];
    const float r0 = bx[1], r1 = bx[2], r2 = bx[3], r3 = bx[4];

    // Level select: h = boxes[:,3]-boxes[:,1], w = boxes[:,4]-boxes[:,2]
    const float area = (r2 - r0) * (r3 - r1);
    const int lvl = (area >= TL2) + (area >= TL3) + (area >= TL4);  // 0..3
    const float* fmap = (lvl == 0) ? f2 : (lvl == 1) ? f3 : (lvl == 2) ? f4 : f5;
    const int H = 256 >> lvl;  // square maps
    const float scale = (lvl == 0) ? 0.25f : (lvl == 1) ? 0.125f
                       : (lvl == 2) ? 0.0625f : 0.03125f;

    const int bidx = (int)b0;

    // _roi_align coords: rois = boxes[:,1:] -> x1=r0, y1=r1, x2=r2, y2=r3
    const float x1 = r0 * scale, y1 = r1 * scale;
    const float x2 = r2 * scale, y2 = r3 * scale;
    const float bw = fmaxf(x2 - x1, 1.0f) * (1.0f / POOL);
    const float bh = fmaxf(y2 - y1, 1.0f) * (1.0f / POOL);
    const float Hf = (float)H, Hm1 = (float)(H - 1);

    // This channel's 3x3 corner, loaded as 3 float4 rows (rows are 128B-aligned)
    const float* plane = fmap + ((size_t)bidx * NCH + (size_t)t) * (size_t)(H * H);
    const float4 row0 = *reinterpret_cast<const float4*>(plane);
    const float4 row1 = *reinterpret_cast<const float4*>(plane + H);
    const float4 row2 = *reinterpret_cast<const float4*>(plane + 2 * H);

    // Separable 3-tap weights per grid position (7 col + 7 row triples).
    float wx0[POOL], wx1[POOL], wx2[POOL];
    float wy0[POOL], wy1[POOL], wy2[POOL];
    #pragma unroll
    for (int p = 0; p < POOL; ++p) {
        const float pc = (float)p + 0.5f;
        {
            float x = x1 + pc * bw;
            bool ok = (x > -1.0f) && (x < Hf);
            float xc = fminf(fmaxf(x, 0.0f), Hm1);
            float x0f = floorf(xc);
            float lx = xc - x0f;
            float hx = 1.0f - lx;
            bool sel = x0f >= 0.5f;             // x0 == 1
            float w0 = sel ? 0.0f : hx;
            float w1 = sel ? hx : lx;
            float w2 = sel ? lx : 0.0f;
            wx0[p] = ok ? w0 : 0.0f;
            wx1[p] = ok ? w1 : 0.0f;
            wx2[p] = ok ? w2 : 0.0f;
        }
        {
            float y = y1 + pc * bh;
            bool ok = (y > -1.0f) && (y < Hf);
            float yc = fminf(fmaxf(y, 0.0f), Hm1);
            float y0f = floorf(yc);
            float ly = yc - y0f;
            float hy = 1.0f - ly;
            bool sel = y0f >= 0.5f;             // y0 == 1
            float w0 = sel ? 0.0f : hy;
            float w1 = sel ? hy : ly;
            float w2 = sel ? ly : 0.0f;
            wy0[p] = ok ? w0 : 0.0f;
            wy1[p] = ok ? w1 : 0.0f;
            wy2[p] = ok ? w2 : 0.0f;
        }
    }

    // Horizontal pass: T[y][px] = sum_x wx[px][x] * corner[y][x]
    float Ty0[POOL], Ty1[POOL], Ty2[POOL];
    #pragma unroll
    for (int p = 0; p < POOL; ++p) {
        Ty0[p] = wx0[p] * row0.x + wx1[p] * row0.y + wx2[p] * row0.z;
        Ty1[p] = wx0[p] * row1.x + wx1[p] * row1.y + wx2[p] * row1.z;
        Ty2[p] = wx0[p] * row2.x + wx1[p] * row2.y + wx2[p] * row2.z;
    }

    // Vertical pass + stash in LDS (thread's 49 results contiguous; lane
    // stride 49 mod 32 = 17 -> <=2-way bank aliasing = free)
    float* myLds = outLds + t * 49;
    #pragma unroll
    for (int py = 0; py < POOL; ++py) {
        #pragma unroll
        for (int px = 0; px < POOL; ++px) {
            myLds[py * 7 + px] =
                wy0[py] * Ty0[px] + wy1[py] * Ty1[px] + wy2[py] * Ty2[px];
        }
    }
    __syncthreads();

    // Coalesced float4 write-out: 12544 floats = 3136 float4 = 12.25/thread
    float* ob = out + (size_t)n * PER_BOX;
    #pragma unroll
    for (int k = 0; k < 12; ++k) {
        int e = 4 * (t + 256 * k);
        float4 v = *reinterpret_cast<const float4*>(outLds + e);
        *reinterpret_cast<float4*>(ob + e) = v;
    }
    if (t < 64) {
        int e = 4 * (t + 3072);
        float4 v = *reinterpret_cast<const float4*>(outLds + e);
        *reinterpret_cast<float4*>(ob + e) = v;
    }
}

extern "C" void kernel_launch(void* const* d_in, const int* in_sizes, int n_in,
                              void* d_out, int out_size, void* d_ws, size_t ws_size,
                              hipStream_t stream) {
    const float* boxes = (const float*)d_in[0];
    const float* f2 = (const float*)d_in[1];
    const float* f3 = (const float*)d_in[2];
    const float* f4 = (const float*)d_in[3];
    const float* f5 = (const float*)d_in[4];
    float* out = (float*)d_out;

    pyramid_roialign_kernel<<<NBOX, 256, 0, stream>>>(boxes, f2, f3, f4, f5, out);
}

// Round 4
// 200.488 us; speedup vs baseline: 1.1570x; 1.0068x over previous
//
#include <hip/hip_runtime.h>

#define POOL 7
#define NCH 256
#define NBOX 1000
#define PER_BOX (NCH * POOL * POOL)  // 12544 floats per box

typedef float v4f __attribute__((ext_vector_type(4)));  // native vec for nontemporal

// Level thresholds on a = h*w for roi_level = round(4 + log2(sqrt(a)*1024/224)),
// clipped to [2,5]. level >= k+1  <=>  a >= (224/1024)^2 * 2^(2k-7).
#define TL2 0.0059814453125f   // -> level >= 3
#define TL3 0.02392578125f     // -> level >= 4
#define TL4 0.095703125f       // -> level >= 5

// One block per box; thread t owns channel t.
// Provable coordinate range: x1,y1 in [0,0.25]; bin = max(roi,1)/7 = 1/7 exactly
// (normalized rois <= 1). Sample coords in (0.07, 1.18) => floor in {0,1},
// no clamping, validity always true, 3-tap corner footprint [0..2].
// Bilinear weights separable: wy depends only on py, wx only on px.
__global__ __launch_bounds__(256) void pyramid_roialign_kernel(
    const float* __restrict__ boxes,
    const float* __restrict__ f2,
    const float* __restrict__ f3,
    const float* __restrict__ f4,
    const float* __restrict__ f5,
    float* __restrict__ out)
{
    __shared__ __align__(16) float outLds[PER_BOX];   // 49 KB -> 3 blocks/CU

    const int n = blockIdx.x;
    const int t = threadIdx.x;

    // Box params (block-uniform -> scalar loads)
    const float* bx = boxes + n * 5;
    const float b0 = bx[0];
    const float r0 = bx[1], r1 = bx[2], r2 = bx[3], r3 = bx[4];

    // Level select
    const float area = (r2 - r0) * (r3 - r1);
    const int lvl = (area >= TL2) + (area >= TL3) + (area >= TL4);  // 0..3
    const float* fmap = (lvl == 0) ? f2 : (lvl == 1) ? f3 : (lvl == 2) ? f4 : f5;
    const int H = 256 >> lvl;
    const float scale = (lvl == 0) ? 0.25f : (lvl == 1) ? 0.125f
                       : (lvl == 2) ? 0.0625f : 0.03125f;
    const int bidx = (int)b0;

    // _roi_align coords (rois = boxes[:,1:]; internal names x1=r0, y1=r1,...)
    const float x1 = r0 * scale, y1 = r1 * scale;
    const float x2 = r2 * scale, y2 = r3 * scale;
    const float bw = fmaxf(x2 - x1, 1.0f) * (1.0f / POOL);
    const float bh = fmaxf(y2 - y1, 1.0f) * (1.0f / POOL);

    // Issue this channel's 3x3 corner loads ASAP (3 x float4 rows)
    const float* plane = fmap + ((size_t)bidx * NCH + (size_t)t) * (size_t)(H * H);
    const float4 row0 = *reinterpret_cast<const float4*>(plane);
    const float4 row1 = *reinterpret_cast<const float4*>(plane + H);
    const float4 row2 = *reinterpret_cast<const float4*>(plane + 2 * H);

    // Separable 3-tap weights. Coord c in (0,1.18): floor(c) = c>=1.
    float wx0[POOL], wx1[POOL], wx2[POOL];
    float wy0[POOL], wy1[POOL], wy2[POOL];
    #pragma unroll
    for (int p = 0; p < POOL; ++p) {
        const float pc = (float)p + 0.5f;
        {
            float x = x1 + pc * bw;
            bool s = x >= 1.0f;
            float xm = s ? x - 1.0f : x;        // fractional part
            float om = 1.0f - xm;
            wx0[p] = s ? 0.0f : om;
            wx1[p] = s ? om : xm;
            wx2[p] = s ? xm : 0.0f;
        }
        {
            float y = y1 + pc * bh;
            bool s = y >= 1.0f;
            float ym = s ? y - 1.0f : y;
            float om = 1.0f - ym;
            wy0[p] = s ? 0.0f : om;
            wy1[p] = s ? om : ym;
            wy2[p] = s ? ym : 0.0f;
        }
    }

    // Horizontal pass: T[y][px] = sum_x wx[px][x] * corner[y][x]
    float Ty0[POOL], Ty1[POOL], Ty2[POOL];
    #pragma unroll
    for (int p = 0; p < POOL; ++p) {
        Ty0[p] = wx0[p] * row0.x + wx1[p] * row0.y + wx2[p] * row0.z;
        Ty1[p] = wx0[p] * row1.x + wx1[p] * row1.y + wx2[p] * row1.z;
        Ty2[p] = wx0[p] * row2.x + wx1[p] * row2.y + wx2[p] * row2.z;
    }

    // Vertical pass -> LDS (lane stride 49 floats: 17t mod 32 => 2-way = free)
    float* myLds = outLds + t * 49;
    #pragma unroll
    for (int py = 0; py < POOL; ++py) {
        #pragma unroll
        for (int px = 0; px < POOL; ++px) {
            myLds[py * 7 + px] =
                wy0[py] * Ty0[px] + wy1[py] * Ty1[px] + wy2[py] * Ty2[px];
        }
    }
    __syncthreads();

    // Coalesced float4 write-out, nontemporal (stream past L2, keep corners hot)
    float* ob = out + (size_t)n * PER_BOX;
    #pragma unroll
    for (int k = 0; k < 12; ++k) {
        int e = 4 * (t + 256 * k);
        v4f v = *reinterpret_cast<const v4f*>(outLds + e);
        __builtin_nontemporal_store(v, reinterpret_cast<v4f*>(ob + e));
    }
    if (t < 64) {
        int e = 4 * (t + 3072);
        v4f v = *reinterpret_cast<const v4f*>(outLds + e);
        __builtin_nontemporal_store(v, reinterpret_cast<v4f*>(ob + e));
    }
}

extern "C" void kernel_launch(void* const* d_in, const int* in_sizes, int n_in,
                              void* d_out, int out_size, void* d_ws, size_t ws_size,
                              hipStream_t stream) {
    const float* boxes = (const float*)d_in[0];
    const float* f2 = (const float*)d_in[1];
    const float* f3 = (const float*)d_in[2];
    const float* f4 = (const float*)d_in[3];
    const float* f5 = (const float*)d_in[4];
    float* out = (float*)d_out;

    pyramid_roialign_kernel<<<NBOX, 256, 0, stream>>>(boxes, f2, f3, f4, f5, out);
}